// Round 9
// baseline (215.848 us; speedup 1.0000x reference)
//
#include <hip/hip_runtime.h>
#include <hip/hip_fp16.h>
#include <stdint.h>

#define BATCH 4096
#define N_IN  512
#define H1    1536
#define H2    1536
#define N_OUT 512
#define E0 (H1 * 32)
#define E1 (H2 * 32)
#define E2 (N_OUT * 32)
#define ETOT (E0 + E1 + E2)
#define NNODES (H1 + H2 + N_OUT)   // 3584 non-input nodes
#define PDEG 80                    // fixed slots/node; Poisson(32) max over 3584 ~54
#define C    16                    // batch columns per block (4096/16 = 256 blocks)

// ---- workspace: edge4 [NNODES][PDEG] u32 entries (src u16 | half(w) u16), then cnt ----
#define EDGE_BYTES ((size_t)NNODES * PDEG * 4)   // 1,146,880
#define OFF_CNT    EDGE_BYTES

// ---------- compact slotted edge fill: entry = src | (half(w) << 16) ----------
__global__ __launch_bounds__(256) void k_fill4(const int* __restrict__ s0, const int* __restrict__ d0, const float* __restrict__ w0,
                                               const int* __restrict__ s1, const int* __restrict__ d1, const float* __restrict__ w1,
                                               const int* __restrict__ s2, const int* __restrict__ d2, const float* __restrict__ w2,
                                               int* __restrict__ cnt, uint32_t* __restrict__ edge4) {
    const int e = blockIdx.x * 256 + threadIdx.x;
    int src, node; float w;
    if (e < E0)           { src = s0[e];          node = d0[e];                 w = w0[e]; }
    else if (e < E0 + E1) { int i = e - E0;       src = s1[i]; node = H1 + d1[i];         w = w1[i]; }
    else                  { int i = e - E0 - E1;  src = s2[i]; node = H1 + H2 + d2[i];    w = w2[i]; }
    const int pos = atomicAdd(&cnt[node], 1);
    if (pos < PDEG) {
        const uint32_t hw = (uint32_t)__half_as_ushort(__float2half_rn(w));
        edge4[(size_t)node * PDEG + pos] = ((uint32_t)src & 0xffffu) | (hw << 16);
    }
}

// ---------- whole-network-in-LDS kernel ----------
// One block owns batch columns [16*bid, 16*bid+16). ALL node values (3584 x 16 fp16
// = 112 KB) live in LDS: the per-CU L1-miss-concurrency cap (~30-40 GB/s/CU random
// gather, measured R4/R7/R8) never applies — gathers are ds_read_b32. Levels are
// block-local (__syncthreads only; no cross-block deps, no transposes).
// Wave layout: 8 waves; a wave processes an octet of 8 dst nodes; lane = sub(3b) x
// colpair(3b): each lane accumulates 2 batch cols of its dst in fp32 regs.
__global__ __launch_bounds__(512, 2)
void k_net(const float* __restrict__ x,
           const uint32_t* __restrict__ edge4,
           const int* __restrict__ cnt,
           float* __restrict__ out) {
    __shared__ __half nvl[NNODES * C];            // 114,688 B
    const int tid  = threadIdx.x;
    const int b0   = blockIdx.x * C;
    const int wave = tid >> 6, lane = tid & 63;
    const int sub  = lane >> 3;                   // dst index within octet (0-7)
    const int cp   = lane & 7;                    // col-pair (covers cols 2*cp, 2*cp+1)

    // ---- stage x: rows 0..511 of nvl (node-major, C cols); coalesced global reads ----
#pragma unroll 4
    for (int i = 0; i < C; ++i)
        nvl[tid * C + i] = __float2half_rn(x[(size_t)(b0 + i) * N_IN + tid]);
    __syncthreads();

    // ---- levels ----
#pragma unroll 1
    for (int l = 0; l < 3; ++l) {
        const int nocts  = (l == 2) ? (N_OUT >> 3) : (H1 >> 3);
        const int ebase  = (l == 0) ? 0 : (l == 1) ? H1 : (H1 + H2);
        const int nvbase = (l == 0) ? N_IN : (N_IN + H1);   // LDS row base for results (l<2)

        for (int o = wave; o < nocts; o += 8) {
            const int ln   = (o << 3) | sub;              // level-local dst
            const int node = ebase + ln;
            int c = cnt[node];
            c = (c < 0) ? 0 : (c > PDEG ? PDEG : c);
            // wave-uniform loop bound: max degree over the octet, rounded to 8
            int qm = c;
#pragma unroll
            for (int s = 8; s < 64; s += 8) {
                const int oc = __builtin_amdgcn_readlane(c, s);
                qm = (oc > qm) ? oc : qm;
            }
            qm = __builtin_amdgcn_readlane(qm, 0);
            // make it a true max across subs (qm at lane0 already saw lanes 8,16,..56 plus its own)
            const int qmax = (qm + 7) & ~7;

            const uint32_t* __restrict__ row = edge4 + (size_t)node * PDEG;
            float a0 = 0.f, a1 = 0.f;
            // software-pipelined 8-slot groups (slots >= c are zero entries: w=0 no-ops)
            uint4 e0 = *(const uint4*)(row);
            uint4 e1 = *(const uint4*)(row + 4);
            for (int j = 0; j < qmax; j += 8) {
                const uint4 n0 = *(const uint4*)(row + j + 8);    // may read pad/next row: in ws, discarded
                const uint4 n1 = *(const uint4*)(row + j + 12);
#define STEP(E) {                                                              \
    const uint32_t ee = (E);                                                   \
    const __half2 vv = *reinterpret_cast<const __half2*>(                      \
        &nvl[(int)(ee & 0xffffu) * C + (cp << 1)]);                            \
    const float wq = __high2float(*reinterpret_cast<const __half2*>(&ee));     \
    a0 = fmaf(__low2float(vv),  wq, a0);                                       \
    a1 = fmaf(__high2float(vv), wq, a1); }
                STEP(e0.x) STEP(e0.y) STEP(e0.z) STEP(e0.w)
                STEP(e1.x) STEP(e1.y) STEP(e1.z) STEP(e1.w)
#undef STEP
                e0 = n0; e1 = n1;
            }
            a0 = fmaxf(a0, 0.f);
            a1 = fmaxf(a1, 0.f);
            if (l < 2) {
                *reinterpret_cast<__half2*>(&nvl[(nvbase + ln) * C + (cp << 1)]) =
                    __floats2half2_rn(a0, a1);
            } else {
                out[(size_t)(b0 + (cp << 1))     * N_OUT + ln] = a0;
                out[(size_t)(b0 + (cp << 1) + 1) * N_OUT + ln] = a1;
            }
        }
        __syncthreads();
    }
}

extern "C" void kernel_launch(void* const* d_in, const int* in_sizes, int n_in,
                              void* d_out, int out_size, void* d_ws, size_t ws_size,
                              hipStream_t stream) {
    const float* x  = (const float*)d_in[0];
    const int* s0   = (const int*)d_in[1];
    const int* dd0  = (const int*)d_in[2];
    const float* w0 = (const float*)d_in[3];
    const int* s1   = (const int*)d_in[4];
    const int* dd1  = (const int*)d_in[5];
    const float* w1 = (const float*)d_in[6];
    const int* s2   = (const int*)d_in[7];
    const int* dd2  = (const int*)d_in[8];
    const float* w2 = (const float*)d_in[9];

    char*     ws    = (char*)d_ws;
    uint32_t* edge4 = (uint32_t*)ws;
    int*      cnt   = (int*)(ws + OFF_CNT);

    // one memset zeroes BOTH edge slots (src=0, w=half(0): harmless pads) and counters
    hipMemsetAsync(ws, 0, EDGE_BYTES + NNODES * sizeof(int), stream);
    k_fill4<<<ETOT / 256, 256, 0, stream>>>(s0, dd0, w0, s1, dd1, w1, s2, dd2, w2, cnt, edge4);

    // whole network: 256 blocks (one per 16-batch slice) x 512 threads
    k_net<<<BATCH / C, 512, 0, stream>>>(x, edge4, cnt, (float*)d_out);
}